// Round 5
// baseline (169.540 us; speedup 1.0000x reference)
//
#include <hip/hip_runtime.h>
#include <hip/hip_bf16.h>

typedef __bf16 bf16_t;
typedef __bf16 bf16x4 __attribute__((ext_vector_type(4)));
typedef __bf16 bf16x8 __attribute__((ext_vector_type(8)));
typedef float floatx4 __attribute__((ext_vector_type(4)));
typedef unsigned int u32;

#define N_NODES 4096
#define F_IN 128
#define NUM_HEADS 4
#define D_HID 64
#define F_OUT 256  // NUM_HEADS * D_HID
#define NEG_SLOPE 0.2f
#define LOG2E 1.4426950408889634f
#define NWORDS 128  // mask u32 words per adjacency row (4096/32)

// ---------------------------------------------------------------------------
// Kernel 0: adjacency -> packed bitmask (1 bit per edge, >=0.5 threshold).
// Pure streaming: 64 MiB read, 2 MiB write.
// ---------------------------------------------------------------------------
__global__ __launch_bounds__(256) void mask_kernel(
    const float* __restrict__ adj, u32* __restrict__ maskw)
{
    const int w = blockIdx.x * 256 + threadIdx.x;   // 0 .. 4096*128-1
    const float* src = adj + (size_t)w * 32;
    u32 bits = 0;
#pragma unroll
    for (int c = 0; c < 8; ++c) {
        const float4 v = *reinterpret_cast<const float4*>(src + c * 4);
        bits |= (u32)(v.x >= 0.5f) << (4 * c + 0);
        bits |= (u32)(v.y >= 0.5f) << (4 * c + 1);
        bits |= (u32)(v.z >= 0.5f) << (4 * c + 2);
        bits |= (u32)(v.w >= 0.5f) << (4 * c + 3);
    }
    maskw[w] = bits;
}

// ---------------------------------------------------------------------------
// Kernel 1: projections (f32 in; GB bf16 fragment-linear + el/er f32 out).
//   GB[h][j>>5][f>>4][lane=(f&15)+16*((j>>3)&3)][j&7]  (1 KB per B-fragment)
//   el/er PRE-SCALED by log2(e) so attn uses exp2 directly.
// ---------------------------------------------------------------------------
__global__ __launch_bounds__(384) void proj_kernel(
    const float* __restrict__ hmat, const float* __restrict__ Wp,
    const float* __restrict__ Wa, const float* __restrict__ wattn,
    bf16_t* __restrict__ GB, float* __restrict__ el, float* __restrict__ er)
{
    const int t = threadIdx.x;
    const int j0 = blockIdx.x * 4;

    float acc[4] = {0.f, 0.f, 0.f, 0.f};

    const float* wptr;
    int stride;
    if (t < 256) { wptr = Wp + t;         stride = 256; }
    else         { wptr = Wa + (t - 256); stride = 128; }

    const float* hbase = hmat + (size_t)j0 * F_IN;

    for (int m = 0; m < F_IN; m += 4) {
        const float w0 = wptr[(size_t)(m + 0) * stride];
        const float w1 = wptr[(size_t)(m + 1) * stride];
        const float w2 = wptr[(size_t)(m + 2) * stride];
        const float w3 = wptr[(size_t)(m + 3) * stride];
#pragma unroll
        for (int jl = 0; jl < 4; ++jl) {
            const float4 hv = *reinterpret_cast<const float4*>(&hbase[jl * F_IN + m]);
            acc[jl] = fmaf(hv.w, w3, fmaf(hv.z, w2, fmaf(hv.y, w1, fmaf(hv.x, w0, acc[jl]))));
        }
    }

    if (t < 256) {
        const int h = t >> 6, f = t & 63;
        bf16x4 o;
#pragma unroll
        for (int q = 0; q < 4; ++q) o[q] = (bf16_t)acc[q];
        const size_t base = ((((size_t)h * 128 + (j0 >> 5)) * 4 + (f >> 4)) * 64
                             + (f & 15) + 16 * ((j0 >> 3) & 3)) * 8 + (j0 & 7);
        *reinterpret_cast<bf16x4*>(&GB[base]) = o;
    } else {
        const int ta = t - 256;          // waves 4,5; 32-lane group per head
        const int ha = ta >> 5, k = ta & 31;
        const float wl = wattn[k] * LOG2E, wr = wattn[32 + k] * LOG2E;
#pragma unroll
        for (int jl = 0; jl < 4; ++jl) {
            float vl = acc[jl] * wl;
            float vr = acc[jl] * wr;
#pragma unroll
            for (int s = 16; s >= 1; s >>= 1) {
                vl += __shfl_xor(vl, s, 64);
                vr += __shfl_xor(vr, s, 64);
            }
            if (k == 0) {
                el[ha * N_NODES + j0 + jl] = vl;
                er[ha * N_NODES + j0 + jl] = vr;
            }
        }
    }
}

// ---------------------------------------------------------------------------
// Kernel 2: barrier-free fused attention. No LDS. 16-row waves.
// Grid (256 i-tiles of 16 rows, 8 jc, 2 head-pairs) x 128 threads (2 waves)
//   = 4096 blocks = 16 blocks/CU = 32 waves/CU (8/SIMD).
// Depth-1 register prefetch of the EARLY-consumed inputs only (mask word,
// e0 quad-slice, b0 fragment) to stay <=64 unified regs at 8 waves/SIMD;
// e1/b1..b3 are consumed >=150cy after issue and ride on TLP.
// Denominator = f32 VALU sum of P (no ones-MFMA, saves AGPRs).
// ---------------------------------------------------------------------------
__global__ __launch_bounds__(128, 8) void attn_kernel(
    const u32* __restrict__ maskw, const bf16_t* __restrict__ GB,
    const float* __restrict__ el, const float* __restrict__ er,
    float* __restrict__ numout, float* __restrict__ den_g,
    int ntiles)
{
    const int tid  = threadIdx.x;
    const int i0   = blockIdx.x * 16;
    const int jc   = blockIdx.y;
    const int hh   = blockIdx.z * 2 + (tid >> 6);   // head
    const int lane = tid & 63;
    const int m    = lane & 15;
    const int quad = lane >> 4;
    const int NS   = ntiles * 2;          // steps of 32 columns
    const int j32_0 = jc * NS;

    const float el_i = el[hh * N_NODES + i0 + m];
    const u32*  mrow = maskw + (size_t)(i0 + m) * NWORDS + j32_0;
    const float* erp = er + hh * N_NODES + j32_0 * 32 + quad * 8;
    const bf16_t* gb = GB + (size_t)hh * (128 * 4 * 512)
                          + (size_t)j32_0 * 2048 + lane * 8;

    floatx4 acc0 = {0.f, 0.f, 0.f, 0.f};
    floatx4 acc1 = acc0, acc2 = acc0, acc3 = acc0;
    float den = 0.f;

    // prologue: prefetch step-0 early-consumed set
    u32 mc = mrow[0];
    float4 e0c = *reinterpret_cast<const float4*>(erp);
    bf16x8 b0c = *reinterpret_cast<const bf16x8*>(gb);

    for (int s = 0; s < NS; ++s) {
        const int sn = (s + 1 < NS) ? s + 1 : s;
        // ---- prefetch next step's early-consumed set ----
        const u32    mn  = mrow[sn];
        const float4 e0n = *reinterpret_cast<const float4*>(erp + (sn - s) * 32);
        const bf16x8 b0n = *reinterpret_cast<const bf16x8*>(gb + (size_t)(sn - s) * 2048);
        // ---- in-step loads (consumed late; TLP covers) ----
        const float4 e1 = *reinterpret_cast<const float4*>(erp + 4);
        const bf16x8 b1 = *reinterpret_cast<const bf16x8*>(gb + 512);
        const bf16x8 b2 = *reinterpret_cast<const bf16x8*>(gb + 1024);
        const bf16x8 b3 = *reinterpret_cast<const bf16x8*>(gb + 1536);

        const u32 by = (mc >> (quad * 8)) & 0xffu;

        float s0 = el_i + e0c.x; s0 = fmaxf(s0, NEG_SLOPE * s0);
        float s1 = el_i + e0c.y; s1 = fmaxf(s1, NEG_SLOPE * s1);
        float s2 = el_i + e0c.z; s2 = fmaxf(s2, NEG_SLOPE * s2);
        float s3 = el_i + e0c.w; s3 = fmaxf(s3, NEG_SLOPE * s3);
        float s4 = el_i + e1.x;  s4 = fmaxf(s4, NEG_SLOPE * s4);
        float s5 = el_i + e1.y;  s5 = fmaxf(s5, NEG_SLOPE * s5);
        float s6 = el_i + e1.z;  s6 = fmaxf(s6, NEG_SLOPE * s6);
        float s7 = el_i + e1.w;  s7 = fmaxf(s7, NEG_SLOPE * s7);

        const float p0 = (by &   1u) ? __builtin_amdgcn_exp2f(s0) : 0.f;
        const float p1 = (by &   2u) ? __builtin_amdgcn_exp2f(s1) : 0.f;
        const float p2 = (by &   4u) ? __builtin_amdgcn_exp2f(s2) : 0.f;
        const float p3 = (by &   8u) ? __builtin_amdgcn_exp2f(s3) : 0.f;
        const float p4 = (by &  16u) ? __builtin_amdgcn_exp2f(s4) : 0.f;
        const float p5 = (by &  32u) ? __builtin_amdgcn_exp2f(s5) : 0.f;
        const float p6 = (by &  64u) ? __builtin_amdgcn_exp2f(s6) : 0.f;
        const float p7 = (by & 128u) ? __builtin_amdgcn_exp2f(s7) : 0.f;

        den += ((p0 + p1) + (p2 + p3)) + ((p4 + p5) + (p6 + p7));

        bf16x8 af;
        af[0] = (bf16_t)p0; af[1] = (bf16_t)p1;
        af[2] = (bf16_t)p2; af[3] = (bf16_t)p3;
        af[4] = (bf16_t)p4; af[5] = (bf16_t)p5;
        af[6] = (bf16_t)p6; af[7] = (bf16_t)p7;

        acc0 = __builtin_amdgcn_mfma_f32_16x16x32_bf16(af, b0c, acc0, 0, 0, 0);
        acc1 = __builtin_amdgcn_mfma_f32_16x16x32_bf16(af, b1, acc1, 0, 0, 0);
        acc2 = __builtin_amdgcn_mfma_f32_16x16x32_bf16(af, b2, acc2, 0, 0, 0);
        acc3 = __builtin_amdgcn_mfma_f32_16x16x32_bf16(af, b3, acc3, 0, 0, 0);

        mc = mn; e0c = e0n; b0c = b0n;
        erp += 32;
        gb  += 2048;
    }

    // cross-quad den reduction: lanes {m, m+16, m+32, m+48} hold row-m partials
    den += __shfl_xor(den, 16, 64);
    den += __shfl_xor(den, 32, 64);

    // epilogue: C/D row = quad*4 + r, col = m
    float* nrow = numout + (size_t)jc * ((size_t)N_NODES * F_OUT);
    const int ib = i0 + quad * 4;
#pragma unroll
    for (int r = 0; r < 4; ++r) {
        float* dst = nrow + (size_t)(ib + r) * F_OUT + hh * D_HID + m;
        dst[0]  = acc0[r];
        dst[16] = acc1[r];
        dst[32] = acc2[r];
        dst[48] = acc3[r];
    }
    if (quad == 0)
        den_g[((size_t)jc * N_NODES + i0 + m) * NUM_HEADS + hh] = den;
}

// ---------------------------------------------------------------------------
// Kernel 3: sum chunk partials, divide, store f32 (float4-vectorized).
// ---------------------------------------------------------------------------
template<int NJC>
__global__ __launch_bounds__(256) void reduce_kernel(
    const float* __restrict__ num, const float* __restrict__ den,
    float* __restrict__ out)
{
    const int t4   = blockIdx.x * 256 + threadIdx.x;  // 0 .. N*F_OUT/4-1
    const int base = t4 * 4;
    const int i  = base >> 8;
    const int hh = (base & 255) >> 6;                 // same head for all 4 ch
    float4 n = {0.f, 0.f, 0.f, 0.f};
    float d = 0.f;
#pragma unroll
    for (int jc = 0; jc < NJC; ++jc) {
        const float4 v = *reinterpret_cast<const float4*>(
            num + (size_t)jc * ((size_t)N_NODES * F_OUT) + base);
        n.x += v.x; n.y += v.y; n.z += v.z; n.w += v.w;
        d += den[((size_t)jc * N_NODES + i) * NUM_HEADS + hh];
    }
    const float rd = 1.0f / d;
    float4 o = {n.x * rd, n.y * rd, n.z * rd, n.w * rd};
    *reinterpret_cast<float4*>(out + base) = o;
}

// ---------------------------------------------------------------------------
extern "C" void kernel_launch(void* const* d_in, const int* in_sizes, int n_in,
                              void* d_out, int out_size, void* d_ws, size_t ws_size,
                              hipStream_t stream)
{
    const float* hmat = (const float*)d_in[0];   // (4096, 128) f32
    const float* adj  = (const float*)d_in[1];   // (4096, 4096) f32
    const float* Wp   = (const float*)d_in[2];   // (128, 256) f32
    const float* Wa   = (const float*)d_in[3];   // (128, 128) f32
    const float* watt = (const float*)d_in[4];   // (64,) f32
    float* out = (float*)d_out;                  // (4096, 256) f32

    char* ws = (char*)d_ws;
    bf16_t* GB   = (bf16_t*)ws;                                  // 2 MiB
    float*  el   = (float*)(ws + (2ull << 20));                  // 64 KiB
    float*  er   = (float*)(ws + (2ull << 20) + (64ull << 10));  // 64 KiB
    u32*    mskw = (u32*)(ws + (2ull << 20) + (128ull << 10));   // 2 MiB
    const size_t baseoff = (4ull << 20) + (128ull << 10);

    const size_t num_bytes = (size_t)N_NODES * F_OUT * 4;          // 4 MiB per chunk
    const size_t den_bytes = (size_t)N_NODES * NUM_HEADS * 4;      // 64 KiB per chunk
    const int njc = (ws_size >= baseoff + 8 * (num_bytes + den_bytes)) ? 8
                  : (ws_size >= baseoff + 4 * (num_bytes + den_bytes)) ? 4 : 2;

    float* num = (float*)(ws + baseoff);
    float* den = (float*)(ws + baseoff + (size_t)njc * num_bytes);

    proj_kernel<<<1024, 384, 0, stream>>>(hmat, Wp, Wa, watt, GB, el, er);
    mask_kernel<<<(N_NODES * NWORDS) / 256, 256, 0, stream>>>(adj, mskw);
    attn_kernel<<<dim3(256, njc, 2), 128, 0, stream>>>(mskw, GB, el, er, num, den,
                                                       (N_NODES / njc) / 64);
    if (njc == 8)      reduce_kernel<8><<<(N_NODES * F_OUT) / 1024, 256, 0, stream>>>(num, den, out);
    else if (njc == 4) reduce_kernel<4><<<(N_NODES * F_OUT) / 1024, 256, 0, stream>>>(num, den, out);
    else               reduce_kernel<2><<<(N_NODES * F_OUT) / 1024, 256, 0, stream>>>(num, den, out);
}

// Round 6
// 165.919 us; speedup vs baseline: 1.0218x; 1.0218x over previous
//
#include <hip/hip_runtime.h>
#include <hip/hip_bf16.h>

typedef __bf16 bf16_t;
typedef __bf16 bf16x4 __attribute__((ext_vector_type(4)));
typedef __bf16 bf16x8 __attribute__((ext_vector_type(8)));
typedef float floatx4 __attribute__((ext_vector_type(4)));
typedef unsigned int u32;

#define N_NODES 4096
#define F_IN 128
#define NUM_HEADS 4
#define D_HID 64
#define F_OUT 256  // NUM_HEADS * D_HID
#define NEG_SLOPE 0.2f
#define LOG2E 1.4426950408889634f
#define NWORDS 128  // mask u32 words per adjacency row (4096/32)

// ---------------------------------------------------------------------------
// Kernel 0: adjacency -> packed bitmask (1 bit per edge, >=0.5 threshold).
// Pure streaming: 64 MiB read, 2 MiB write.
// ---------------------------------------------------------------------------
__global__ __launch_bounds__(256) void mask_kernel(
    const float* __restrict__ adj, u32* __restrict__ maskw)
{
    const int w = blockIdx.x * 256 + threadIdx.x;   // 0 .. 4096*128-1
    const float* src = adj + (size_t)w * 32;
    u32 bits = 0;
#pragma unroll
    for (int c = 0; c < 8; ++c) {
        const float4 v = *reinterpret_cast<const float4*>(src + c * 4);
        bits |= (u32)(v.x >= 0.5f) << (4 * c + 0);
        bits |= (u32)(v.y >= 0.5f) << (4 * c + 1);
        bits |= (u32)(v.z >= 0.5f) << (4 * c + 2);
        bits |= (u32)(v.w >= 0.5f) << (4 * c + 3);
    }
    maskw[w] = bits;
}

// ---------------------------------------------------------------------------
// Kernel 1: projections (f32 in; GB bf16 fragment-linear + el/er f32 out).
//   GB[h][j>>5][f>>4][lane=(f&15)+16*((j>>3)&3)][j&7]  (1 KB per B-fragment)
//   el/er PRE-SCALED by log2(e) so attn uses exp2 directly.
// 512 blocks x 384 threads; block handles 8 nodes (halves W re-read traffic;
// the 8 contiguous j's make the GB store a single bf16x8).
// ---------------------------------------------------------------------------
__global__ __launch_bounds__(384) void proj_kernel(
    const float* __restrict__ hmat, const float* __restrict__ Wp,
    const float* __restrict__ Wa, const float* __restrict__ wattn,
    bf16_t* __restrict__ GB, float* __restrict__ el, float* __restrict__ er)
{
    const int t = threadIdx.x;
    const int j0 = blockIdx.x * 8;

    float acc[8] = {0.f, 0.f, 0.f, 0.f, 0.f, 0.f, 0.f, 0.f};

    const float* wptr;
    int stride;
    if (t < 256) { wptr = Wp + t;         stride = 256; }
    else         { wptr = Wa + (t - 256); stride = 128; }

    const float* hbase = hmat + (size_t)j0 * F_IN;

    for (int m = 0; m < F_IN; m += 4) {
        const float w0 = wptr[(size_t)(m + 0) * stride];
        const float w1 = wptr[(size_t)(m + 1) * stride];
        const float w2 = wptr[(size_t)(m + 2) * stride];
        const float w3 = wptr[(size_t)(m + 3) * stride];
#pragma unroll
        for (int jl = 0; jl < 8; ++jl) {
            const float4 hv = *reinterpret_cast<const float4*>(&hbase[jl * F_IN + m]);
            acc[jl] = fmaf(hv.w, w3, fmaf(hv.z, w2, fmaf(hv.y, w1, fmaf(hv.x, w0, acc[jl]))));
        }
    }

    if (t < 256) {
        const int h = t >> 6, f = t & 63;
        bf16x8 o;
#pragma unroll
        for (int q = 0; q < 8; ++q) o[q] = (bf16_t)acc[q];
        // j0 % 8 == 0: the 8 nodes fill one contiguous [j&7] run
        const size_t base = ((((size_t)h * 128 + (j0 >> 5)) * 4 + (f >> 4)) * 64
                             + (f & 15) + 16 * ((j0 >> 3) & 3)) * 8;
        *reinterpret_cast<bf16x8*>(&GB[base]) = o;
    } else {
        const int ta = t - 256;          // waves 4,5; 32-lane group per head
        const int ha = ta >> 5, k = ta & 31;
        const float wl = wattn[k] * LOG2E, wr = wattn[32 + k] * LOG2E;
#pragma unroll
        for (int jl = 0; jl < 8; ++jl) {
            float vl = acc[jl] * wl;
            float vr = acc[jl] * wr;
#pragma unroll
            for (int s = 16; s >= 1; s >>= 1) {
                vl += __shfl_xor(vl, s, 64);
                vr += __shfl_xor(vr, s, 64);
            }
            if (k == 0) {
                el[ha * N_NODES + j0 + jl] = vl;
                er[ha * N_NODES + j0 + jl] = vr;
            }
        }
    }
}

// ---------------------------------------------------------------------------
// Kernel 2: barrier-free fused attention. No LDS. 32-row waves, full
// depth-1 register prefetch (mask words, er, all 4 B-fragments).
// Grid (32 i-tiles of 128 rows, 8 jc, 4 heads) x 256 threads (4 waves)
//   = 1024 blocks = 4 blocks/CU = 16 waves/CU (4/SIMD).
// The 4 waves of a block share ONE head: their per-step GB/er addresses are
// IDENTICAL (i-independent) -> 3 of 4 reads hit L1; GB L2 traffic drops 4x
// (512->64 MB). Mask rows differ per wave (i-dependent) but are tiny.
// Denominator = f32 VALU sum of P values.
// ---------------------------------------------------------------------------
__global__ __launch_bounds__(256, 4) void attn_kernel(
    const u32* __restrict__ maskw, const bf16_t* __restrict__ GB,
    const float* __restrict__ el, const float* __restrict__ er,
    float* __restrict__ numout, float* __restrict__ den_g,
    int ntiles)
{
    const int tid  = threadIdx.x;
    const int wave = tid >> 6;
    const int i0   = blockIdx.x * 128 + wave * 32;
    const int jc   = blockIdx.y;
    const int hh   = blockIdx.z;
    const int lane = tid & 63;
    const int m    = lane & 15;
    const int quad = lane >> 4;
    const int NS   = ntiles * 2;          // steps of 32 columns
    const int j32_0 = jc * NS;

    const float el_lo = el[hh * N_NODES + i0 + m];
    const float el_hi = el[hh * N_NODES + i0 + 16 + m];
    const u32*  mrowL = maskw + (size_t)(i0 + m) * NWORDS + j32_0;
    const u32*  mrowH = mrowL + (size_t)16 * NWORDS;
    const float* erp  = er + hh * N_NODES + j32_0 * 32 + quad * 8;
    const bf16_t* gb  = GB + (size_t)hh * (128 * 4 * 512)
                           + (size_t)j32_0 * 2048 + lane * 8;

    floatx4 accL0 = {0.f, 0.f, 0.f, 0.f};
    floatx4 accL1 = accL0, accL2 = accL0, accL3 = accL0;
    floatx4 accH0 = accL0, accH1 = accL0, accH2 = accL0, accH3 = accL0;
    float denL = 0.f, denH = 0.f;

    // prologue: full step-0 set in registers
    u32 mLc = mrowL[0], mHc = mrowH[0];
    float4 e0c = *reinterpret_cast<const float4*>(erp);
    float4 e1c = *reinterpret_cast<const float4*>(erp + 4);
    bf16x8 b0c = *reinterpret_cast<const bf16x8*>(gb);
    bf16x8 b1c = *reinterpret_cast<const bf16x8*>(gb + 512);
    bf16x8 b2c = *reinterpret_cast<const bf16x8*>(gb + 1024);
    bf16x8 b3c = *reinterpret_cast<const bf16x8*>(gb + 1536);

    for (int s = 0; s < NS; ++s) {
        const int d = (s + 1 < NS) ? 1 : 0;   // clamp on last step
        // ---- depth-1 prefetch of the ENTIRE next-step set ----
        const u32    mLn = mrowL[d];
        const u32    mHn = mrowH[d];
        const float4 e0n = *reinterpret_cast<const float4*>(erp + d * 32);
        const float4 e1n = *reinterpret_cast<const float4*>(erp + d * 32 + 4);
        const bf16_t* gpn = gb + (size_t)d * 2048;
        const bf16x8 b0n = *reinterpret_cast<const bf16x8*>(gpn);
        const bf16x8 b1n = *reinterpret_cast<const bf16x8*>(gpn + 512);
        const bf16x8 b2n = *reinterpret_cast<const bf16x8*>(gpn + 1024);
        const bf16x8 b3n = *reinterpret_cast<const bf16x8*>(gpn + 1536);

        // ---- P fragments for 32 rows x 32 cols (this wave) ----
        const u32 byL = (mLc >> (quad * 8)) & 0xffu;
        const u32 byH = (mHc >> (quad * 8)) & 0xffu;
        const float ev[8] = {e0c.x, e0c.y, e0c.z, e0c.w, e1c.x, e1c.y, e1c.z, e1c.w};

        bf16x8 afL, afH;
        float dL = 0.f, dH = 0.f;
#pragma unroll
        for (int q = 0; q < 8; ++q) {
            float sL = el_lo + ev[q]; sL = fmaxf(sL, NEG_SLOPE * sL);
            float sH = el_hi + ev[q]; sH = fmaxf(sH, NEG_SLOPE * sH);
            const float pL = ((byL >> q) & 1u) ? __builtin_amdgcn_exp2f(sL) : 0.f;
            const float pH = ((byH >> q) & 1u) ? __builtin_amdgcn_exp2f(sH) : 0.f;
            dL += pL; dH += pH;
            afL[q] = (bf16_t)pL;
            afH[q] = (bf16_t)pH;
        }
        denL += dL; denH += dH;

        accL0 = __builtin_amdgcn_mfma_f32_16x16x32_bf16(afL, b0c, accL0, 0, 0, 0);
        accH0 = __builtin_amdgcn_mfma_f32_16x16x32_bf16(afH, b0c, accH0, 0, 0, 0);
        accL1 = __builtin_amdgcn_mfma_f32_16x16x32_bf16(afL, b1c, accL1, 0, 0, 0);
        accH1 = __builtin_amdgcn_mfma_f32_16x16x32_bf16(afH, b1c, accH1, 0, 0, 0);
        accL2 = __builtin_amdgcn_mfma_f32_16x16x32_bf16(afL, b2c, accL2, 0, 0, 0);
        accH2 = __builtin_amdgcn_mfma_f32_16x16x32_bf16(afH, b2c, accH2, 0, 0, 0);
        accL3 = __builtin_amdgcn_mfma_f32_16x16x32_bf16(afL, b3c, accL3, 0, 0, 0);
        accH3 = __builtin_amdgcn_mfma_f32_16x16x32_bf16(afH, b3c, accH3, 0, 0, 0);

        // rotate prefetched set in
        mLc = mLn; mHc = mHn; e0c = e0n; e1c = e1n;
        b0c = b0n; b1c = b1n; b2c = b2n; b3c = b3n;
        mrowL += 1; mrowH += 1;
        erp += 32;
        gb  += 2048;
    }

    // cross-quad den reduction (lanes {m,m+16,m+32,m+48} hold row partials)
    denL += __shfl_xor(denL, 16, 64);
    denL += __shfl_xor(denL, 32, 64);
    denH += __shfl_xor(denH, 16, 64);
    denH += __shfl_xor(denH, 32, 64);

    // epilogue: C/D row = quad*4 + r (lo) / +16 (hi), col = m
    float* nrow = numout + (size_t)jc * ((size_t)N_NODES * F_OUT);
    const int ibL = i0 + quad * 4;
    const int ibH = ibL + 16;
#pragma unroll
    for (int r = 0; r < 4; ++r) {
        float* dL = nrow + (size_t)(ibL + r) * F_OUT + hh * D_HID + m;
        dL[0]  = accL0[r];
        dL[16] = accL1[r];
        dL[32] = accL2[r];
        dL[48] = accL3[r];
        float* dH = nrow + (size_t)(ibH + r) * F_OUT + hh * D_HID + m;
        dH[0]  = accH0[r];
        dH[16] = accH1[r];
        dH[32] = accH2[r];
        dH[48] = accH3[r];
    }
    if (quad == 0) {
        den_g[((size_t)jc * N_NODES + i0 + m) * NUM_HEADS + hh] = denL;
        den_g[((size_t)jc * N_NODES + i0 + 16 + m) * NUM_HEADS + hh] = denH;
    }
}

// ---------------------------------------------------------------------------
// Kernel 3: sum chunk partials, divide, store f32 (float4-vectorized).
// ---------------------------------------------------------------------------
template<int NJC>
__global__ __launch_bounds__(256) void reduce_kernel(
    const float* __restrict__ num, const float* __restrict__ den,
    float* __restrict__ out)
{
    const int t4   = blockIdx.x * 256 + threadIdx.x;  // 0 .. N*F_OUT/4-1
    const int base = t4 * 4;
    const int i  = base >> 8;
    const int hh = (base & 255) >> 6;                 // same head for all 4 ch
    float4 n = {0.f, 0.f, 0.f, 0.f};
    float d = 0.f;
#pragma unroll
    for (int jc = 0; jc < NJC; ++jc) {
        const float4 v = *reinterpret_cast<const float4*>(
            num + (size_t)jc * ((size_t)N_NODES * F_OUT) + base);
        n.x += v.x; n.y += v.y; n.z += v.z; n.w += v.w;
        d += den[((size_t)jc * N_NODES + i) * NUM_HEADS + hh];
    }
    const float rd = 1.0f / d;
    float4 o = {n.x * rd, n.y * rd, n.z * rd, n.w * rd};
    *reinterpret_cast<float4*>(out + base) = o;
}

// ---------------------------------------------------------------------------
extern "C" void kernel_launch(void* const* d_in, const int* in_sizes, int n_in,
                              void* d_out, int out_size, void* d_ws, size_t ws_size,
                              hipStream_t stream)
{
    const float* hmat = (const float*)d_in[0];   // (4096, 128) f32
    const float* adj  = (const float*)d_in[1];   // (4096, 4096) f32
    const float* Wp   = (const float*)d_in[2];   // (128, 256) f32
    const float* Wa   = (const float*)d_in[3];   // (128, 128) f32
    const float* watt = (const float*)d_in[4];   // (64,) f32
    float* out = (float*)d_out;                  // (4096, 256) f32

    char* ws = (char*)d_ws;
    bf16_t* GB   = (bf16_t*)ws;                                  // 2 MiB
    float*  el   = (float*)(ws + (2ull << 20));                  // 64 KiB
    float*  er   = (float*)(ws + (2ull << 20) + (64ull << 10));  // 64 KiB
    u32*    mskw = (u32*)(ws + (2ull << 20) + (128ull << 10));   // 2 MiB
    const size_t baseoff = (4ull << 20) + (128ull << 10);

    const size_t num_bytes = (size_t)N_NODES * F_OUT * 4;          // 4 MiB per chunk
    const size_t den_bytes = (size_t)N_NODES * NUM_HEADS * 4;      // 64 KiB per chunk
    const int njc = (ws_size >= baseoff + 8 * (num_bytes + den_bytes)) ? 8
                  : (ws_size >= baseoff + 4 * (num_bytes + den_bytes)) ? 4 : 2;

    float* num = (float*)(ws + baseoff);
    float* den = (float*)(ws + baseoff + (size_t)njc * num_bytes);

    proj_kernel<<<512, 384, 0, stream>>>(hmat, Wp, Wa, watt, GB, el, er);
    mask_kernel<<<(N_NODES * NWORDS) / 256, 256, 0, stream>>>(adj, mskw);
    attn_kernel<<<dim3(32, njc, NUM_HEADS), 256, 0, stream>>>(
        mskw, GB, el, er, num, den, (N_NODES / njc) / 64);
    if (njc == 8)      reduce_kernel<8><<<(N_NODES * F_OUT) / 1024, 256, 0, stream>>>(num, den, out);
    else if (njc == 4) reduce_kernel<4><<<(N_NODES * F_OUT) / 1024, 256, 0, stream>>>(num, den, out);
    else               reduce_kernel<2><<<(N_NODES * F_OUT) / 1024, 256, 0, stream>>>(num, den, out);
}